// Round 9
// baseline (234.502 us; speedup 1.0000x reference)
//
#include <hip/hip_runtime.h>
#include <hip/hip_fp16.h>
#include <math.h>

// Problem constants: B=2, K=128, L=4096, DK=DL=128, HID=128
constexpr int BB = 2;
constexpr int KK = 128;
constexpr int LL = 4096;
constexpr int DD = 128;
constexpr int HH = 128;
constexpr int NBLK = 512;   // 2 blocks/CU, all co-resident

__device__ __forceinline__ float4 ld4(const float* p) {
    return *reinterpret_cast<const float4*>(p);
}

// packed fp16 max — emits v_pk_max_f16
__device__ __forceinline__ __half2 hmax2(__half2 a, __half2 b) {
    unsigned ua = __builtin_bit_cast(unsigned, a);
    unsigned ub = __builtin_bit_cast(unsigned, b);
    unsigned ud;
    asm("v_pk_max_f16 %0, %1, %2" : "=v"(ud) : "v"(ua), "v"(ub));
    return __builtin_bit_cast(__half2, ud);
}

// duplicate fp16(x) into both halves of a dword
__device__ __forceinline__ uint32_t duph(float x) {
    __half h = __float2half(x);
    unsigned short us = __builtin_bit_cast(unsigned short, h);
    return (uint32_t)us * 0x10001u;
}

// agent-scope device barrier (R7-proven pattern). cnt/flag zeroed per replay
// by the memset node. Register state survives (only tid 0 spins).
__device__ __forceinline__ void devbar(int* cnt, int* flag) {
    __syncthreads();
    if (threadIdx.x == 0) {
        __threadfence();
        int old = __hip_atomic_fetch_add(cnt, 1, __ATOMIC_ACQ_REL,
                                         __HIP_MEMORY_SCOPE_AGENT);
        if (old == NBLK - 1) {
            __hip_atomic_store(flag, 1, __ATOMIC_RELEASE,
                               __HIP_MEMORY_SCOPE_AGENT);
        } else {
            while (__hip_atomic_load(flag, __ATOMIC_ACQUIRE,
                                     __HIP_MEMORY_SCOPE_AGENT) == 0)
                __builtin_amdgcn_s_sleep(2);
        }
    }
    __syncthreads();
    __threadfence();
}

// ---------------------------------------------------------------------------
// Single persistent kernel. 512 blocks x 256 threads.
// P1 (blocks 0..263): GEMM tiles of 32 rows.
//   blocks 0..255: B-tiles, XCD-swizzled: x=bid&7, y=bid>>3, chunk C=x+8*(y&1)
//   (512 l of batch C>>3), sub s=y>>1 -> rows C*512+s*32. Writer XCD = C%8.
//   blocks 256..263: A-tiles -> u_dup; block 256 packs w2_dup.
// barrier A
// P2 (all): block m: cb=m&7 (l-chunk, XCD cb = writer XCD), kt=(m>>3)&31 (4 k),
//   b=m>>8. Thread: 1 l-pair x 4 k. fp16 pk scores (16-h f32 flush), then
//   block softmax partials (pmax/psum per row-chunk); t stays in registers.
// barrier B
// P3: combine 8 chunk-partials per row (uniform loads), out = t * factor.
// ---------------------------------------------------------------------------
__global__ __launch_bounds__(256, 2) void fused(
    const float* __restrict__ inA, const float* __restrict__ inB,
    const float* __restrict__ W1, const float* __restrict__ b1,
    const float* __restrict__ w2,
    uint32_t* __restrict__ u_dup, uint32_t* __restrict__ w2_dup,
    __half* __restrict__ vT,
    float* __restrict__ pmax_g, float* __restrict__ psum_g,
    int* __restrict__ bar, float* __restrict__ out)
{
    __shared__ __align__(16) float sIn[32 * 128];   // 16 KiB
    __shared__ float sT[128 * 33];                  // 16.9 KiB (reused as red)

    const int tid = threadIdx.x;
    const int bid = blockIdx.x;

    // ============================ P1: GEMM ================================
    if (bid < 264) {
        int row0;
        bool isA;
        if (bid < 256) {
            const int x = bid & 7, y = bid >> 3;
            const int C = x + 8 * (y & 1);
            const int s = y >> 1;
            row0 = C * 512 + s * 32;    // B virtual row (b*4096 + l)
            isA = false;
        } else {
            row0 = (bid - 256) * 32;    // u row
            isA = true;
        }
        const float* src = (isA ? inA : inB) + (size_t)row0 * DD;
        const float* w   = W1 + (isA ? 0 : DD * HH);

        #pragma unroll
        for (int j = 0; j < 4; ++j) {
            const int idx = tid + 256 * j;
            reinterpret_cast<float4*>(sIn)[idx] =
                reinterpret_cast<const float4*>(src)[idx];
        }
        __syncthreads();

        const int tx = tid & 31;
        const int ty = tid >> 5;

        float accx[4], accy[4], accz[4], accw[4];
        #pragma unroll
        for (int r = 0; r < 4; ++r) { accx[r] = accy[r] = accz[r] = accw[r] = 0.f; }

        for (int d0 = 0; d0 < DD; d0 += 4) {
            float4 w4[4];
            #pragma unroll
            for (int dd = 0; dd < 4; ++dd)
                w4[dd] = ld4(&w[(size_t)(d0 + dd) * HH + tx * 4]);
            float a[4][4];
            #pragma unroll
            for (int r = 0; r < 4; ++r) {
                float4 a4 = ld4(&sIn[(ty * 4 + r) * 128 + d0]);
                a[r][0] = a4.x; a[r][1] = a4.y; a[r][2] = a4.z; a[r][3] = a4.w;
            }
            #pragma unroll
            for (int dd = 0; dd < 4; ++dd) {
                const float4 wv = w4[dd];
                #pragma unroll
                for (int r = 0; r < 4; ++r) {
                    const float av = a[r][dd];
                    accx[r] = fmaf(av, wv.x, accx[r]);
                    accy[r] = fmaf(av, wv.y, accy[r]);
                    accz[r] = fmaf(av, wv.z, accz[r]);
                    accw[r] = fmaf(av, wv.w, accw[r]);
                }
            }
        }

        if (isA) {
            const float4 bb = ld4(&b1[tx * 4]);
            #pragma unroll
            for (int r = 0; r < 4; ++r) {
                uint4 o;
                o.x = duph(accx[r] + bb.x);
                o.y = duph(accy[r] + bb.y);
                o.z = duph(accz[r] + bb.z);
                o.w = duph(accw[r] + bb.w);
                *reinterpret_cast<uint4*>(
                    &u_dup[(size_t)(row0 + ty * 4 + r) * HH + tx * 4]) = o;
            }
            if (bid == 256 && tid < HH) w2_dup[tid] = duph(w2[tid]);
        } else {
            #pragma unroll
            for (int r = 0; r < 4; ++r) {
                const int l = ty * 4 + r;
                sT[(tx * 4 + 0) * 33 + l] = accx[r];
                sT[(tx * 4 + 1) * 33 + l] = accy[r];
                sT[(tx * 4 + 2) * 33 + l] = accz[r];
                sT[(tx * 4 + 3) * 33 + l] = accw[r];
            }
            __syncthreads();
            const int h    = tid >> 1;
            const int half = tid & 1;
            const int bsel = row0 >> 12;
            const int l0   = (row0 & 4095) + half * 16;
            uint32_t o[8];
            #pragma unroll
            for (int i = 0; i < 8; ++i) {
                const float lo = sT[h * 33 + half * 16 + 2 * i];
                const float hi = sT[h * 33 + half * 16 + 2 * i + 1];
                o[i] = __builtin_bit_cast(uint32_t, __floats2half2_rn(lo, hi));
            }
            uint32_t* dst = reinterpret_cast<uint32_t*>(vT) +
                            (size_t)(bsel * HH + h) * (LL / 2) + l0 / 2;
            uint4 s0; s0.x = o[0]; s0.y = o[1]; s0.z = o[2]; s0.w = o[3];
            uint4 s1; s1.x = o[4]; s1.y = o[5]; s1.z = o[6]; s1.w = o[7];
            *reinterpret_cast<uint4*>(dst)     = s0;
            *reinterpret_cast<uint4*>(dst + 4) = s1;
        }
    }

    devbar(&bar[0], &bar[16]);

    // ==================== P2: scores + partial softmax ====================
    int mm = bid;
    const int cb = mm & 7;   mm >>= 3;
    const int kt = mm & 31;  mm >>= 5;
    const int b  = mm;

    uint32_t* sU = reinterpret_cast<uint32_t*>(sIn);   // 4*HH dwords
    uint32_t* sW = sU + 4 * HH;
    if (tid < 128)
        reinterpret_cast<uint4*>(sU)[tid] =
            reinterpret_cast<const uint4*>(u_dup + (size_t)(b * KK + kt * 4) * HH)[tid];
    else if (tid < 160)
        reinterpret_cast<uint4*>(sW)[tid - 128] =
            reinterpret_cast<const uint4*>(w2_dup)[tid - 128];
    __syncthreads();

    const int p = cb * 256 + tid;   // l-pair index within b
    const uint32_t* vp = reinterpret_cast<const uint32_t*>(vT)
                         + (size_t)b * HH * (LL / 2) + p;

    const __half2 hz = __float2half2_rn(0.f);
    float2 facc[4];
    #pragma unroll
    for (int k = 0; k < 4; ++k) { facc[k].x = 0.f; facc[k].y = 0.f; }

    for (int g = 0; g < 8; ++g) {
        const int h0 = g * 16;
        uint32_t v[16];
        #pragma unroll
        for (int jj = 0; jj < 16; ++jj)
            v[jj] = vp[(size_t)(h0 + jj) * (LL / 2)];

        __half2 acc[4];
        #pragma unroll
        for (int k = 0; k < 4; ++k) acc[k] = hz;

        #pragma unroll
        for (int k = 0; k < 4; ++k) {
            #pragma unroll
            for (int q = 0; q < 4; ++q) {
                const uint4 uc = *reinterpret_cast<const uint4*>(&sU[k * HH + h0 + q * 4]);
                const uint4 wc = *reinterpret_cast<const uint4*>(&sW[h0 + q * 4]);
                const uint32_t* uq = reinterpret_cast<const uint32_t*>(&uc);
                const uint32_t* wq = reinterpret_cast<const uint32_t*>(&wc);
                #pragma unroll
                for (int jj = 0; jj < 4; ++jj) {
                    const __half2 uu = __builtin_bit_cast(__half2, uq[jj]);
                    const __half2 ww = __builtin_bit_cast(__half2, wq[jj]);
                    __half2 t = __hadd2(__builtin_bit_cast(__half2, v[q * 4 + jj]), uu);
                    acc[k] = __hfma2(hmax2(t, hz), ww, acc[k]);
                }
            }
        }
        #pragma unroll
        for (int k = 0; k < 4; ++k) {
            const float2 f = __half22float2(acc[k]);
            facc[k].x += f.x; facc[k].y += f.y;
        }
    }

    // block-local max per k-row
    __syncthreads();            // sT free for reductions
    float* red = sT;
    float mx[4];
    #pragma unroll
    for (int k = 0; k < 4; ++k) {
        mx[k] = fmaxf(facc[k].x, facc[k].y);
        #pragma unroll
        for (int off = 32; off > 0; off >>= 1)
            mx[k] = fmaxf(mx[k], __shfl_xor(mx[k], off, 64));
    }
    const int lane = tid & 63, wv = tid >> 6;
    if (lane == 0) {
        red[wv * 4 + 0] = mx[0]; red[wv * 4 + 1] = mx[1];
        red[wv * 4 + 2] = mx[2]; red[wv * 4 + 3] = mx[3];
    }
    __syncthreads();
    float M[4];
    #pragma unroll
    for (int k = 0; k < 4; ++k)
        M[k] = fmaxf(fmaxf(red[k], red[4 + k]), fmaxf(red[8 + k], red[12 + k]));
    __syncthreads();

    // t = exp(s - M_local), block-local sums
    float sm[4];
    #pragma unroll
    for (int k = 0; k < 4; ++k) {
        facc[k].x = expf(facc[k].x - M[k]);
        facc[k].y = expf(facc[k].y - M[k]);
        sm[k] = facc[k].x + facc[k].y;
        #pragma unroll
        for (int off = 32; off > 0; off >>= 1)
            sm[k] += __shfl_xor(sm[k], off, 64);
    }
    if (lane == 0) {
        red[wv * 4 + 0] = sm[0]; red[wv * 4 + 1] = sm[1];
        red[wv * 4 + 2] = sm[2]; red[wv * 4 + 3] = sm[3];
    }
    __syncthreads();
    if (tid == 0) {
        const int rowb = (b * KK + kt * 4) * 8 + cb;
        #pragma unroll
        for (int k = 0; k < 4; ++k) {
            const float S = (red[k] + red[4 + k]) + (red[8 + k] + red[12 + k]);
            pmax_g[rowb + k * 8] = M[k];
            psum_g[rowb + k * 8] = S;
        }
    }

    devbar(&bar[32], &bar[48]);

    // ==================== P3: combine + final store =======================
    const int rowbase = b * KK + kt * 4;
    float fac[4];
    #pragma unroll
    for (int k = 0; k < 4; ++k) {
        const float* pm = &pmax_g[(size_t)(rowbase + k) * 8];
        const float* ps = &psum_g[(size_t)(rowbase + k) * 8];
        float Mg = pm[0];
        #pragma unroll
        for (int c = 1; c < 8; ++c) Mg = fmaxf(Mg, pm[c]);
        float Sg = 0.f;
        #pragma unroll
        for (int c = 0; c < 8; ++c) Sg += ps[c] * expf(pm[c] - Mg);
        fac[k] = expf(M[k] - Mg) / Sg;
    }
    #pragma unroll
    for (int k = 0; k < 4; ++k) {
        float2 o;
        o.x = facc[k].x * fac[k];
        o.y = facc[k].y * fac[k];
        *reinterpret_cast<float2*>(
            &out[(size_t)(rowbase + k) * LL + 2 * p]) = o;
    }
}

// ---------------------------------------------------------------------------
extern "C" void kernel_launch(void* const* d_in, const int* in_sizes, int n_in,
                              void* d_out, int out_size, void* d_ws, size_t ws_size,
                              hipStream_t stream)
{
    const float* inA = (const float*)d_in[0];
    const float* inB = (const float*)d_in[1];
    const float* W1  = (const float*)d_in[2];
    const float* b1  = (const float*)d_in[3];
    const float* w2  = (const float*)d_in[4];
    float* out = (float*)d_out;

    char* ws = (char*)d_ws;
    uint32_t* u_dup  = (uint32_t*)ws;                      // 128 KiB @ 0
    uint32_t* w2_dup = (uint32_t*)(ws + 0x20000);          // 512 B
    __half*   vT     = (__half*)(ws + 0x40000);            // 2 MiB
    float*    pmax_g = (float*)(ws + 0x240000);            // 8 KiB
    float*    psum_g = (float*)(ws + 0x242000);            // 8 KiB
    int*      bar    = (int*)(ws + 0x250000);              // 256 B

    hipMemsetAsync(bar, 0, 256, stream);
    hipLaunchKernelGGL(fused, dim3(NBLK), dim3(256), 0, stream,
                       inA, inB, W1, b1, w2, u_dup, w2_dup, vT,
                       pmax_g, psum_g, bar, out);
}

// Round 10
// 30.685 us; speedup vs baseline: 7.6423x; 7.6423x over previous
//
#include <hip/hip_runtime.h>
#include <hip/hip_fp16.h>
#include <math.h>

// Problem constants: B=2, K=128, L=4096, DK=DL=128, HID=128
constexpr int BB = 2;
constexpr int KK = 128;
constexpr int LL = 4096;
constexpr int DD = 128;
constexpr int HH = 128;

__device__ __forceinline__ float4 ld4(const float* p) {
    return *reinterpret_cast<const float4*>(p);
}

// packed fp16 max — emits v_pk_max_f16
__device__ __forceinline__ __half2 hmax2(__half2 a, __half2 b) {
    unsigned ua = __builtin_bit_cast(unsigned, a);
    unsigned ub = __builtin_bit_cast(unsigned, b);
    unsigned ud;
    asm("v_pk_max_f16 %0, %1, %2" : "=v"(ud) : "v"(ua), "v"(ub));
    return __builtin_bit_cast(__half2, ud);
}

// duplicate fp16(x) into both halves of a dword
__device__ __forceinline__ uint32_t duph(float x) {
    __half h = __float2half(x);
    unsigned short us = __builtin_bit_cast(unsigned short, h);
    return (uint32_t)us * 0x10001u;
}

// ---------------------------------------------------------------------------
// K1: 264 blocks x 256 threads, 32 virtual rows each.
//   W1-half (64 KB) is staged into LDS in two 32 KB chunks so the inner loop
//   never touches global for W (removes the unhidden L2-latency that dominated
//   R1-R8). Input tile (16 KB) staged once. Transpose tile sT overlays the sW
//   region after compute (sync-protected).
//   B-tiles XCD-swizzled: x=bid&7, y=bid>>3 (y<32), chunk C=x+8*(y&1),
//   rows C*512 + (y>>1)*32 -> writer XCD = C%8 matches k2 readers.
//   blocks 256..263: A-tiles -> u_dup (dup'd fp16); block 256 packs w2_dup.
// ---------------------------------------------------------------------------
__global__ __launch_bounds__(256) void k1_gemm(
    const float* __restrict__ inA, const float* __restrict__ inB,
    const float* __restrict__ W1, const float* __restrict__ b1,
    const float* __restrict__ w2,
    uint32_t* __restrict__ u_dup, uint32_t* __restrict__ w2_dup,
    __half* __restrict__ vT)
{
    __shared__ __align__(16) char smem[49 * 1024];
    float*  sIn = reinterpret_cast<float*>(smem);               // 16 KiB
    float4* sW4 = reinterpret_cast<float4*>(smem + 16 * 1024);  // 32 KiB (64 d-rows)
    float*  sT  = reinterpret_cast<float*>(smem + 16 * 1024);   // 17 KiB overlay

    const int bid = blockIdx.x;
    const int tid = threadIdx.x;

    int row0;            // first row within its own space
    bool isA;
    if (bid < 256) {
        const int x = bid & 7, y = bid >> 3;
        const int C = x + 8 * (y & 1);
        row0 = C * 512 + (y >> 1) * 32;    // B virtual row (b*4096 + l)
        isA = false;
    } else {
        row0 = (bid - 256) * 32;           // u row
        isA = true;
    }
    const float* src = (isA ? inA : inB) + (size_t)row0 * DD;
    const float4* wsrc = reinterpret_cast<const float4*>(W1 + (isA ? 0 : DD * HH));

    // stage 32x128 input tile (coalesced float4)
    #pragma unroll
    for (int j = 0; j < 4; ++j) {
        const int idx = tid + 256 * j;
        reinterpret_cast<float4*>(sIn)[idx] =
            reinterpret_cast<const float4*>(src)[idx];
    }

    const int tx = tid & 31;   // h-cols tx*4 .. tx*4+3
    const int ty = tid >> 5;   // rows ty*4 .. ty*4+3

    float accx[4], accy[4], accz[4], accw[4];
    #pragma unroll
    for (int r = 0; r < 4; ++r) { accx[r] = accy[r] = accz[r] = accw[r] = 0.f; }

    // two 64-d-row halves of W staged through the same 32 KB LDS buffer
    for (int wh = 0; wh < 2; ++wh) {
        __syncthreads();     // sIn ready (first iter) / sW draining (second)
        #pragma unroll
        for (int q = 0; q < 8; ++q)
            sW4[tid + 256 * q] = wsrc[wh * 2048 + tid + 256 * q];
        __syncthreads();

        #pragma unroll 2
        for (int dd0 = 0; dd0 < 64; dd0 += 4) {
            const int d0 = wh * 64 + dd0;
            float4 w4[4];
            #pragma unroll
            for (int dd = 0; dd < 4; ++dd)
                w4[dd] = sW4[(dd0 + dd) * 32 + tx];
            float a[4][4];
            #pragma unroll
            for (int r = 0; r < 4; ++r) {
                float4 a4 = ld4(&sIn[(ty * 4 + r) * 128 + d0]);
                a[r][0] = a4.x; a[r][1] = a4.y; a[r][2] = a4.z; a[r][3] = a4.w;
            }
            #pragma unroll
            for (int dd = 0; dd < 4; ++dd) {
                const float4 wv = w4[dd];
                #pragma unroll
                for (int r = 0; r < 4; ++r) {
                    const float av = a[r][dd];
                    accx[r] = fmaf(av, wv.x, accx[r]);
                    accy[r] = fmaf(av, wv.y, accy[r]);
                    accz[r] = fmaf(av, wv.z, accz[r]);
                    accw[r] = fmaf(av, wv.w, accw[r]);
                }
            }
        }
    }

    if (isA) {
        const float4 bb = ld4(&b1[tx * 4]);
        #pragma unroll
        for (int r = 0; r < 4; ++r) {
            uint4 o;
            o.x = duph(accx[r] + bb.x);
            o.y = duph(accy[r] + bb.y);
            o.z = duph(accz[r] + bb.z);
            o.w = duph(accw[r] + bb.w);
            *reinterpret_cast<uint4*>(
                &u_dup[(size_t)(row0 + ty * 4 + r) * HH + tx * 4]) = o;
        }
        if (bid == 256 && tid < HH) w2_dup[tid] = duph(w2[tid]);
    } else {
        __syncthreads();   // sT overlays sW: wait until all waves done reading
        #pragma unroll
        for (int r = 0; r < 4; ++r) {
            const int l = ty * 4 + r;
            sT[(tx * 4 + 0) * 33 + l] = accx[r];
            sT[(tx * 4 + 1) * 33 + l] = accy[r];
            sT[(tx * 4 + 2) * 33 + l] = accz[r];
            sT[(tx * 4 + 3) * 33 + l] = accw[r];
        }
        __syncthreads();
        const int h    = tid >> 1;
        const int half = tid & 1;
        const int bsel = row0 >> 12;
        const int l0   = (row0 & 4095) + half * 16;
        uint32_t o[8];
        #pragma unroll
        for (int i = 0; i < 8; ++i) {
            const float lo = sT[h * 33 + half * 16 + 2 * i];
            const float hi = sT[h * 33 + half * 16 + 2 * i + 1];
            o[i] = __builtin_bit_cast(uint32_t, __floats2half2_rn(lo, hi));
        }
        uint32_t* dst = reinterpret_cast<uint32_t*>(vT) +
                        (size_t)(bsel * HH + h) * (LL / 2) + l0 / 2;
        uint4 s0; s0.x = o[0]; s0.y = o[1]; s0.z = o[2]; s0.w = o[3];
        uint4 s1; s1.x = o[4]; s1.y = o[5]; s1.z = o[6]; s1.w = o[7];
        *reinterpret_cast<uint4*>(dst)     = s0;
        *reinterpret_cast<uint4*>(dst + 4) = s1;
    }
}

// ---------------------------------------------------------------------------
// K2: scores. 512 blocks x 256 threads. Block m = cb + 8*q, q = kt + 32*b ->
// reader XCD cb matches k1's writer XCD for that v-chunk. Thread: 1 l-pair x
// 4 k. u(4 rows)+w2 in LDS; v as batched dwords; fp16 acc, f32 flush per 16 h.
// ---------------------------------------------------------------------------
__global__ __launch_bounds__(256) void k2_score(
    const uint32_t* __restrict__ u_dup, const uint32_t* __restrict__ w2_dup,
    const __half* __restrict__ vT, float* __restrict__ out)
{
    __shared__ __align__(16) uint32_t sU[4 * HH];   // 2 KiB
    __shared__ __align__(16) uint32_t sW[HH];       // 512 B

    int m = blockIdx.x;
    const int cb = m & 7;   m >>= 3;
    const int kt = m & 31;  m >>= 5;
    const int b  = m;
    const int tid = threadIdx.x;

    if (tid < 128)
        reinterpret_cast<uint4*>(sU)[tid] =
            reinterpret_cast<const uint4*>(u_dup + (size_t)(b * KK + kt * 4) * HH)[tid];
    else if (tid < 160)
        reinterpret_cast<uint4*>(sW)[tid - 128] =
            reinterpret_cast<const uint4*>(w2_dup)[tid - 128];
    __syncthreads();

    const int p = cb * 256 + tid;   // l-pair index within b; l = 2p
    const uint32_t* vp = reinterpret_cast<const uint32_t*>(vT)
                         + (size_t)b * HH * (LL / 2) + p;

    const __half2 hz = __float2half2_rn(0.f);
    float2 facc[4];
    #pragma unroll
    for (int k = 0; k < 4; ++k) { facc[k].x = 0.f; facc[k].y = 0.f; }

    for (int g = 0; g < 8; ++g) {          // 16 h per group
        const int h0 = g * 16;
        uint32_t v[16];
        #pragma unroll
        for (int jj = 0; jj < 16; ++jj)
            v[jj] = vp[(size_t)(h0 + jj) * (LL / 2)];

        __half2 acc[4];
        #pragma unroll
        for (int k = 0; k < 4; ++k) acc[k] = hz;

        #pragma unroll
        for (int q = 0; q < 4; ++q) {
            const uint4 wc = *reinterpret_cast<const uint4*>(&sW[h0 + q * 4]);
            uint4 uc[4];
            #pragma unroll
            for (int k = 0; k < 4; ++k)
                uc[k] = *reinterpret_cast<const uint4*>(&sU[k * HH + h0 + q * 4]);
            const uint32_t* wq = reinterpret_cast<const uint32_t*>(&wc);
            #pragma unroll
            for (int jj = 0; jj < 4; ++jj) {
                const __half2 ww = __builtin_bit_cast(__half2, wq[jj]);
                const __half2 vv = __builtin_bit_cast(__half2, v[q * 4 + jj]);
                #pragma unroll
                for (int k = 0; k < 4; ++k) {
                    const uint32_t* uq = reinterpret_cast<const uint32_t*>(&uc[k]);
                    __half2 t = __hadd2(vv, __builtin_bit_cast(__half2, uq[jj]));
                    acc[k] = __hfma2(hmax2(t, hz), ww, acc[k]);
                }
            }
        }
        #pragma unroll
        for (int k = 0; k < 4; ++k) {
            const float2 f = __half22float2(acc[k]);
            facc[k].x += f.x; facc[k].y += f.y;
        }
    }

    #pragma unroll
    for (int k = 0; k < 4; ++k)
        *reinterpret_cast<float2*>(
            &out[(size_t)(b * KK + kt * 4 + k) * LL + 2 * p]) = facc[k];
}

// ---------------------------------------------------------------------------
// K3: in-place row softmax. 256 blocks x 1024 threads.
// ---------------------------------------------------------------------------
__global__ __launch_bounds__(1024) void k3_softmax(float* __restrict__ out)
{
    __shared__ float redm[16];
    __shared__ float reds[16];

    const int row = blockIdx.x;
    float* p = out + (size_t)row * LL;
    const int tid = threadIdx.x;

    float4 x = reinterpret_cast<const float4*>(p)[tid];

    float m = fmaxf(fmaxf(x.x, x.y), fmaxf(x.z, x.w));
    #pragma unroll
    for (int off = 32; off > 0; off >>= 1)
        m = fmaxf(m, __shfl_xor(m, off, 64));
    const int lane = tid & 63, wv = tid >> 6;
    if (lane == 0) redm[wv] = m;
    __syncthreads();
    if (tid < 16) {
        float mm = redm[tid];
        #pragma unroll
        for (int off = 8; off > 0; off >>= 1)
            mm = fmaxf(mm, __shfl_xor(mm, off, 64));
        redm[tid] = mm;
    }
    __syncthreads();
    m = redm[0];

    x.x = expf(x.x - m); x.y = expf(x.y - m);
    x.z = expf(x.z - m); x.w = expf(x.w - m);
    float s = (x.x + x.y) + (x.z + x.w);
    #pragma unroll
    for (int off = 32; off > 0; off >>= 1)
        s += __shfl_xor(s, off, 64);
    if (lane == 0) reds[wv] = s;
    __syncthreads();
    if (tid < 16) {
        float ss = reds[tid];
        #pragma unroll
        for (int off = 8; off > 0; off >>= 1)
            ss += __shfl_xor(ss, off, 64);
        reds[tid] = ss;
    }
    __syncthreads();
    s = reds[0];

    const float inv = 1.0f / s;
    x.x *= inv; x.y *= inv; x.z *= inv; x.w *= inv;
    reinterpret_cast<float4*>(p)[tid] = x;
}

// ---------------------------------------------------------------------------
extern "C" void kernel_launch(void* const* d_in, const int* in_sizes, int n_in,
                              void* d_out, int out_size, void* d_ws, size_t ws_size,
                              hipStream_t stream)
{
    const float* inA = (const float*)d_in[0];
    const float* inB = (const float*)d_in[1];
    const float* W1  = (const float*)d_in[2];
    const float* b1  = (const float*)d_in[3];
    const float* w2  = (const float*)d_in[4];
    float* out = (float*)d_out;

    char* ws = (char*)d_ws;
    uint32_t* u_dup  = (uint32_t*)ws;                      // 128 KiB
    uint32_t* w2_dup = (uint32_t*)(ws + 0x20000);          // 512 B
    __half*   vT     = (__half*)(ws + 0x40000);            // 2 MiB

    hipLaunchKernelGGL(k1_gemm, dim3(264), dim3(256), 0, stream,
                       inA, inB, W1, b1, w2, u_dup, w2_dup, vT);
    hipLaunchKernelGGL(k2_score, dim3(512), dim3(256), 0, stream,
                       u_dup, w2_dup, vT, out);
    hipLaunchKernelGGL(k3_softmax, dim3(BB * KK), dim3(1024), 0, stream, out);
}